// Round 3
// baseline (20793.237 us; speedup 1.0000x reference)
//
#include <hip/hip_runtime.h>
#include <cstdint>

// Problem constants (MusicVAEDecoder)
#define B_   64
#define Z_   512
#define U_   2048
#define NL_  3
#define T_   32
#define DIN_ 90
#define G4_  8192      // 4*U
#define STLD 12288     // st row stride = NL*2*U  (h_l = st + l*4096, c_l = +2048)

// GEMM tile config: 64 rows (all B) x 32 cols per block, K-tile 128 in LDS
#define THREADS 256
#define TK  128
#define TKP 129        // padded LDS stride (conflict-free)
#define TN  32

// thread map: cg = t&7 -> 4 cols each (32 cols), rg = t>>3 -> 2 rows each (64 rows)
__device__ __forceinline__ void gemm_body(const float* __restrict__ A, int lda,
                                          const float* __restrict__ W, int ldw,
                                          int K, int jb, float acc[2][4],
                                          float* ldsA, int t)
{
    const int cg = t & 7, rg = t >> 3;
    const int r0 = rg * 2;
    for (int kt = 0; kt < K; kt += TK) {
        __syncthreads();
        // stage A[0:64][kt:kt+TK] into LDS (coalesced: consecutive t -> consecutive kk)
        for (int x = t; x < 64 * TK; x += THREADS) {
            int r = x >> 7, kk = x & (TK - 1);
            ldsA[r * TKP + kk] = A[(size_t)r * lda + kt + kk];
        }
        __syncthreads();
        const float* Wp = W + (size_t)kt * ldw + jb + cg * 4;
        #pragma unroll 8
        for (int kk = 0; kk < TK; ++kk) {
            float4 w = *(const float4*)(Wp);
            Wp += ldw;
            float a0 = ldsA[(r0 + 0) * TKP + kk];
            float a1 = ldsA[(r0 + 1) * TKP + kk];
            acc[0][0] += a0 * w.x; acc[0][1] += a0 * w.y;
            acc[0][2] += a0 * w.z; acc[0][3] += a0 * w.w;
            acc[1][0] += a1 * w.x; acc[1][1] += a1 * w.y;
            acc[1][2] += a1 * w.z; acc[1][3] += a1 * w.w;
        }
    }
}

// out[64 x N] (row stride ldo) = A(64 x K) @ W(K x N) + init
// mode 0: init = initBuf (64 x ldo buffer); mode 1: init = bias[j]; mode 2: out += A@W
__global__ __launch_bounds__(THREADS) void gemm64(
    const float* __restrict__ A, int lda,
    const float* __restrict__ W, int ldw,
    float* __restrict__ out, int ldo,
    const float* __restrict__ initBuf, const float* __restrict__ bias,
    int K, int mode)
{
    __shared__ float ldsA[64 * TKP];
    const int t = threadIdx.x;
    const int jb = blockIdx.x * TN;
    float acc[2][4] = {};
    gemm_body(A, lda, W, ldw, K, jb, acc, ldsA, t);

    const int cg = t & 7, rg = t >> 3;
    const int j = jb + cg * 4;
    #pragma unroll
    for (int ri = 0; ri < 2; ++ri) {
        const int row = rg * 2 + ri;
        float* op = out + (size_t)row * ldo + j;
        float4 v = make_float4(acc[ri][0], acc[ri][1], acc[ri][2], acc[ri][3]);
        if (mode == 0) {
            float4 ib = *(const float4*)(initBuf + (size_t)row * ldo + j);
            v.x += ib.x; v.y += ib.y; v.z += ib.z; v.w += ib.w;
        } else if (mode == 1) {
            float4 bb = *(const float4*)(bias + j);
            v.x += bb.x; v.y += bb.y; v.z += bb.z; v.w += bb.w;
        } else {
            float4 ov = *(const float4*)op;
            v.x += ov.x; v.y += ov.y; v.z += ov.z; v.w += ov.w;
        }
        *(float4*)op = v;
    }
}

// fused recurrent GEMMs for the 3 layers: zg_l = init_l + h_l @ rk_l  (blockIdx.y = layer)
__global__ __launch_bounds__(THREADS) void rec3(
    const float* __restrict__ st,
    const float* __restrict__ rk0, const float* __restrict__ rk1, const float* __restrict__ rk2,
    const float* __restrict__ xk0, const float* __restrict__ b1v, const float* __restrict__ b2v,
    float* __restrict__ zg0, float* __restrict__ zg1, float* __restrict__ zg2)
{
    __shared__ float ldsA[64 * TKP];
    const int t = threadIdx.x;
    const int ly = blockIdx.y;
    const int jb = blockIdx.x * TN;
    const float* A = st + ly * (2 * U_);           // h_l view, lda = STLD
    const float* W = (ly == 0) ? rk0 : (ly == 1) ? rk1 : rk2;
    float* out     = (ly == 0) ? zg0 : (ly == 1) ? zg1 : zg2;

    float acc[2][4] = {};
    gemm_body(A, STLD, W, G4_, U_, jb, acc, ldsA, t);

    const int cg = t & 7, rg = t >> 3;
    const int j = jb + cg * 4;
    #pragma unroll
    for (int ri = 0; ri < 2; ++ri) {
        const int row = rg * 2 + ri;
        float4 v = make_float4(acc[ri][0], acc[ri][1], acc[ri][2], acc[ri][3]);
        if (ly == 0) {
            float4 ib = *(const float4*)(xk0 + (size_t)row * G4_ + j);
            v.x += ib.x; v.y += ib.y; v.z += ib.z; v.w += ib.w;
        } else {
            const float* bv = (ly == 1) ? b1v : b2v;
            float4 bb = *(const float4*)(bv + j);
            v.x += bb.x; v.y += bb.y; v.z += bb.z; v.w += bb.w;
        }
        *(float4*)(out + (size_t)row * G4_ + j) = v;
    }
}

__device__ __forceinline__ float sigf(float x) { return 1.f / (1.f + expf(-x)); }

// LSTM gate update for layer `layer`: reads zg (64 x 8192), updates h,c views in st
__global__ __launch_bounds__(256) void gate_kernel(const float* __restrict__ zg,
                                                   float* __restrict__ st, int layer)
{
    const int idx = blockIdx.x * 256 + threadIdx.x;   // 0 .. 64*2048-1
    const int b = idx >> 11, u = idx & (U_ - 1);
    const float* zr = zg + (size_t)b * G4_;
    const float gi = zr[u];
    const float gf = zr[U_ + u];
    const float gg = zr[2 * U_ + u];
    const float go = zr[3 * U_ + u];
    float* hp = st + (size_t)b * STLD + layer * (2 * U_) + u;
    float* cp = hp + U_;
    const float c  = *cp;
    const float cn = sigf(gf) * c + sigf(gi) * tanhf(gg);
    const float hn = sigf(go) * tanhf(cn);
    *cp = cn;
    *hp = hn;
}

// out[b][tstep][:] = h2[b] @ w_out + b_out   (one block per batch row)
__global__ __launch_bounds__(128) void outproj(const float* __restrict__ st,
                                               const float* __restrict__ w_out,
                                               const float* __restrict__ b_out,
                                               float* __restrict__ out, int tstep)
{
    __shared__ float lh[U_];
    const int b = blockIdx.x, t = threadIdx.x;
    const float* h2 = st + (size_t)b * STLD + 2 * (2 * U_);
    for (int x = t; x < U_; x += 128) lh[x] = h2[x];
    __syncthreads();
    if (t < DIN_) {
        float a0 = 0.f, a1 = 0.f, a2 = 0.f, a3 = 0.f;
        for (int k = 0; k < U_; k += 4) {
            a0 += lh[k + 0] * w_out[(size_t)(k + 0) * DIN_ + t];
            a1 += lh[k + 1] * w_out[(size_t)(k + 1) * DIN_ + t];
            a2 += lh[k + 2] * w_out[(size_t)(k + 2) * DIN_ + t];
            a3 += lh[k + 3] * w_out[(size_t)(k + 3) * DIN_ + t];
        }
        out[(size_t)b * T_ * DIN_ + tstep * DIN_ + t] = a0 + a1 + a2 + a3 + b_out[t];
    }
}

extern "C" void kernel_launch(void* const* d_in, const int* in_sizes, int n_in,
                              void* d_out, int out_size, void* d_ws, size_t ws_size,
                              hipStream_t stream)
{
    const float* z      = (const float*)d_in[0];
    const float* w_init = (const float*)d_in[1];
    const float* b_init = (const float*)d_in[2];
    const float* k0     = (const float*)d_in[3];
    const float* rk0    = (const float*)d_in[4];
    const float* b0     = (const float*)d_in[5];
    const float* k1     = (const float*)d_in[6];
    const float* rk1    = (const float*)d_in[7];
    const float* b1     = (const float*)d_in[8];
    const float* k2     = (const float*)d_in[9];
    const float* rk2    = (const float*)d_in[10];
    const float* b2     = (const float*)d_in[11];
    const float* w_out  = (const float*)d_in[12];
    const float* b_out  = (const float*)d_in[13];
    float* out = (float*)d_out;

    // workspace layout (floats): st | zg0 | zg1 | zg2 | xk0   (~11 MB total)
    float* ws  = (float*)d_ws;
    float* st  = ws;
    float* zg0 = st  + (size_t)B_ * STLD;
    float* zg1 = zg0 + (size_t)B_ * G4_;
    float* zg2 = zg1 + (size_t)B_ * G4_;
    float* xk0 = zg2 + (size_t)B_ * G4_;
    (void)ws_size; (void)in_sizes; (void)n_in; (void)out_size;

    // S1: st = z @ w_init + b_init   (h/c initial states, viewed in place)
    gemm64<<<dim3(STLD / TN), THREADS, 0, stream>>>(z, Z_, w_init, STLD, st, STLD,
                                                    nullptr, b_init, Z_, 1);
    // S2: xk0 = z @ k0[90:,:] + b0   (constant input contribution, hoisted out of time loop)
    gemm64<<<dim3(G4_ / TN), THREADS, 0, stream>>>(z, Z_, k0 + (size_t)DIN_ * G4_, G4_,
                                                   xk0, G4_, nullptr, b0, Z_, 1);

    for (int tstep = 0; tstep < T_; ++tstep) {
        // all three recurrent GEMMs are independent -> one fused launch (768 blocks)
        rec3<<<dim3(G4_ / TN, 3), THREADS, 0, stream>>>(st, rk0, rk1, rk2,
                                                        xk0, b1, b2, zg0, zg1, zg2);
        gate_kernel<<<dim3(B_ * U_ / 256), 256, 0, stream>>>(zg0, st, 0);
        gemm64<<<dim3(G4_ / TN), THREADS, 0, stream>>>(st, STLD, k1, G4_, zg1, G4_,
                                                       nullptr, nullptr, U_, 2);
        gate_kernel<<<dim3(B_ * U_ / 256), 256, 0, stream>>>(zg1, st, 1);
        gemm64<<<dim3(G4_ / TN), THREADS, 0, stream>>>(st + 2 * U_, STLD, k2, G4_, zg2, G4_,
                                                       nullptr, nullptr, U_, 2);
        gate_kernel<<<dim3(B_ * U_ / 256), 256, 0, stream>>>(zg2, st, 2);
        outproj<<<dim3(B_), 128, 0, stream>>>(st, w_out, b_out, out, tstep);
    }
}

// Round 4
// 7265.517 us; speedup vs baseline: 2.8619x; 2.8619x over previous
//
#include <hip/hip_runtime.h>
#include <cstdint>

// Problem constants
#define B_   64
#define Z_   512
#define U_   2048
#define T_   32
#define DIN_ 90
#define G4_  8192      // 4*U
#define STLD 12288     // st row stride (fp32 h/c state): h_l = +l*4096, c_l = +l*4096+2048

using bf16x8 = __attribute__((ext_vector_type(8))) short;   // 8 bf16 = 4 VGPRs
using f32x4  = __attribute__((ext_vector_type(4))) float;

#define MFMA(a, b, c) __builtin_amdgcn_mfma_f32_16x16x32_bf16((a), (b), (c), 0, 0, 0)

__device__ __forceinline__ unsigned short f2bf(float f) {
    unsigned int u = __float_as_uint(f);
    unsigned int r = (u + 0x7FFFu + ((u >> 16) & 1u)) >> 16;   // RNE
    return (unsigned short)r;
}
__device__ __forceinline__ float sigf(float x) { return 1.f / (1.f + expf(-x)); }

// ---------------- one-time weight prep ----------------

// Wt[n*K + k] = bf16(W[(row_off+k)*N + n])  -- transpose + convert
__global__ __launch_bounds__(256) void transpose_cvt(const float* __restrict__ W,
                                                     unsigned short* __restrict__ Wt,
                                                     int K, int N, int row_off)
{
    __shared__ float tile[32][33];
    const int nb = blockIdx.x * 32, kb = blockIdx.y * 32;
    const int tx = threadIdx.x & 31, ty = threadIdx.x >> 5;   // 32 x 8
    #pragma unroll
    for (int i = 0; i < 4; ++i)
        tile[ty + i * 8][tx] = W[(size_t)(row_off + kb + ty + i * 8) * N + nb + tx];
    __syncthreads();
    #pragma unroll
    for (int i = 0; i < 4; ++i)
        Wt[(size_t)(nb + ty + i * 8) * K + kb + tx] = f2bf(tile[tx][ty + i * 8]);
}

__global__ __launch_bounds__(256) void cvt_z(const float* __restrict__ z,
                                             unsigned short* __restrict__ zb)
{
    int i = blockIdx.x * 256 + threadIdx.x;        // 64*512
    zb[i] = f2bf(z[i]);
}

// initial h (from st fp32) -> bf16 ping buffers
__global__ __launch_bounds__(256) void hinit(const float* __restrict__ st,
                                             unsigned short* __restrict__ h0,
                                             unsigned short* __restrict__ h1,
                                             unsigned short* __restrict__ h2)
{
    int idx = blockIdx.x * 256 + threadIdx.x;      // 3*64*2048
    int u = idx & 2047, b = (idx >> 11) & 63, ly = idx >> 17;
    float v = st[(size_t)b * STLD + ly * 4096 + u];
    unsigned short* h = (ly == 0) ? h0 : (ly == 1) ? h1 : h2;
    h[(size_t)b * 2048 + u] = f2bf(v);
}

// ---------------- setup GEMMs (K=512): out[64 x N] = A @ Wt^T + bias ----------------
// block: 64 rows x 64 cols, 4 waves (2x2), wave tile 32x32
__global__ __launch_bounds__(256) void gemm_plain(const unsigned short* __restrict__ A, int K,
                                                  const unsigned short* __restrict__ Wt,
                                                  const float* __restrict__ bias,
                                                  float* __restrict__ out, int ldo)
{
    const int t = threadIdx.x, wv = t >> 6, l = t & 63;
    const int wm = (wv >> 1) * 32, n0 = blockIdx.x * 64 + (wv & 1) * 32;
    const int lr = l & 15, lk = (l >> 4) * 8;
    f32x4 acc[2][2] = {};
    for (int kt = 0; kt < K; kt += 32) {
        bf16x8 a0 = *(const bf16x8*)(A + (size_t)(wm + lr) * K + kt + lk);
        bf16x8 a1 = *(const bf16x8*)(A + (size_t)(wm + 16 + lr) * K + kt + lk);
        bf16x8 w0 = *(const bf16x8*)(Wt + (size_t)(n0 + lr) * K + kt + lk);
        bf16x8 w1 = *(const bf16x8*)(Wt + (size_t)(n0 + 16 + lr) * K + kt + lk);
        acc[0][0] = MFMA(a0, w0, acc[0][0]);
        acc[0][1] = MFMA(a0, w1, acc[0][1]);
        acc[1][0] = MFMA(a1, w0, acc[1][0]);
        acc[1][1] = MFMA(a1, w1, acc[1][1]);
    }
    #pragma unroll
    for (int mi = 0; mi < 2; ++mi)
        #pragma unroll
        for (int ni = 0; ni < 2; ++ni)
            #pragma unroll
            for (int r = 0; r < 4; ++r) {
                int row = wm + mi * 16 + (l >> 4) * 4 + r;
                int col = n0 + ni * 16 + lr;
                out[(size_t)row * ldo + col] = acc[mi][ni][r] + bias[col];
            }
}

// ---------------- gate epilogue (shared) ----------------
// sh[4][64][17]; wave (g, half) wrote its S+add values; then 512 threads gate 1024 (b,u)
__device__ __forceinline__ void gate_apply(float (*sh)[64][17], float* __restrict__ st,
                                           unsigned short* __restrict__ hbnew,
                                           int ly, int u0, int t)
{
    __syncthreads();
    #pragma unroll
    for (int i = 0; i < 2; ++i) {
        int idx = t + i * 512;                 // 0..1023
        int b = idx >> 4, uu = idx & 15, u = u0 + uu;
        float gi = sh[0][b][uu], gf = sh[1][b][uu], gg = sh[2][b][uu], go = sh[3][b][uu];
        float* cp = st + (size_t)b * STLD + ly * 4096 + 2048 + u;
        float c  = *cp;
        float cn = sigf(gf) * c + sigf(gi) * tanhf(gg);
        float hn = sigf(go) * tanhf(cn);
        *cp = cn;
        st[(size_t)b * STLD + ly * 4096 + u] = hn;       // fp32 h (outproj uses layer2)
        hbnew[(size_t)b * 2048 + u] = f2bf(hn);
    }
}

// ---------------- fused recurrent launch: 3 layers, layer0 gated ----------------
// grid (128, 3), block 512 (8 waves: g=wv&3 gate group, half=wv>>2 row half)
// ly==0: S = hb0_old @ rk0T + xk0  -> gate0 -> c0, h0(new)
// ly>0 : zg_l = hb_l_old @ rk_lT + b_l   (k-contribution added later)
__global__ __launch_bounds__(512) void recA(
    const unsigned short* __restrict__ hb0, const unsigned short* __restrict__ hb1,
    const unsigned short* __restrict__ hb2,
    const unsigned short* __restrict__ rk0T, const unsigned short* __restrict__ rk1T,
    const unsigned short* __restrict__ rk2T,
    const float* __restrict__ xk0, const float* __restrict__ b1v, const float* __restrict__ b2v,
    float* __restrict__ zg1, float* __restrict__ zg2,
    float* __restrict__ st, unsigned short* __restrict__ hb0_new)
{
    __shared__ float sh[4][64][17];
    const int ly = blockIdx.y;
    const unsigned short* A  = (ly == 0) ? hb0 : (ly == 1) ? hb1 : hb2;
    const unsigned short* Wt = (ly == 0) ? rk0T : (ly == 1) ? rk1T : rk2T;
    const int t = threadIdx.x, wv = t >> 6, l = t & 63;
    const int g = wv & 3, half = wv >> 2;
    const int u0 = blockIdx.x * 16;
    const int lr = l & 15, lk = (l >> 4) * 8;
    const int ncol = g * 2048 + u0 + lr;
    const unsigned short* wp = Wt + (size_t)ncol * 2048 + lk;
    const unsigned short* ap = A + (size_t)(half * 32 + lr) * 2048 + lk;

    f32x4 acc[2] = {};
    #pragma unroll 4
    for (int kt = 0; kt < 2048; kt += 32) {
        bf16x8 wf = *(const bf16x8*)(wp + kt);
        bf16x8 a0 = *(const bf16x8*)(ap + kt);
        bf16x8 a1 = *(const bf16x8*)(ap + 16 * 2048 + kt);
        acc[0] = MFMA(a0, wf, acc[0]);
        acc[1] = MFMA(a1, wf, acc[1]);
    }

    if (ly == 0) {
        #pragma unroll
        for (int mi = 0; mi < 2; ++mi)
            #pragma unroll
            for (int r = 0; r < 4; ++r) {
                int row = half * 32 + mi * 16 + (l >> 4) * 4 + r;
                sh[g][row][lr] = acc[mi][r] + xk0[(size_t)row * G4_ + g * 2048 + u0 + lr];
            }
        gate_apply(sh, st, hb0_new, 0, u0, t);
    } else {
        float* zg = (ly == 1) ? zg1 : zg2;
        const float* bias = (ly == 1) ? b1v : b2v;
        float bv = bias[g * 2048 + u0 + lr];
        #pragma unroll
        for (int mi = 0; mi < 2; ++mi)
            #pragma unroll
            for (int r = 0; r < 4; ++r) {
                int row = half * 32 + mi * 16 + (l >> 4) * 4 + r;
                zg[(size_t)row * G4_ + g * 2048 + u0 + lr] = acc[mi][r] + bv;
            }
    }
}

// ---------------- k-input GEMM + gate for layer ly (1 or 2) ----------------
// grid 128, block 512. S = A(new lower h) @ kT + zg_l  -> gate -> c, h(new)
__global__ __launch_bounds__(512) void kgate(
    const unsigned short* __restrict__ A, const unsigned short* __restrict__ kT,
    const float* __restrict__ zg, float* __restrict__ st,
    unsigned short* __restrict__ hbnew, int ly)
{
    __shared__ float sh[4][64][17];
    const int t = threadIdx.x, wv = t >> 6, l = t & 63;
    const int g = wv & 3, half = wv >> 2;
    const int u0 = blockIdx.x * 16;
    const int lr = l & 15, lk = (l >> 4) * 8;
    const int ncol = g * 2048 + u0 + lr;
    const unsigned short* wp = kT + (size_t)ncol * 2048 + lk;
    const unsigned short* ap = A + (size_t)(half * 32 + lr) * 2048 + lk;

    f32x4 acc[2] = {};
    #pragma unroll 4
    for (int kt = 0; kt < 2048; kt += 32) {
        bf16x8 wf = *(const bf16x8*)(wp + kt);
        bf16x8 a0 = *(const bf16x8*)(ap + kt);
        bf16x8 a1 = *(const bf16x8*)(ap + 16 * 2048 + kt);
        acc[0] = MFMA(a0, wf, acc[0]);
        acc[1] = MFMA(a1, wf, acc[1]);
    }
    #pragma unroll
    for (int mi = 0; mi < 2; ++mi)
        #pragma unroll
        for (int r = 0; r < 4; ++r) {
            int row = half * 32 + mi * 16 + (l >> 4) * 4 + r;
            sh[g][row][lr] = acc[mi][r] + zg[(size_t)row * G4_ + g * 2048 + u0 + lr];
        }
    gate_apply(sh, st, hbnew, ly, u0, t);
}

// ---------------- output projection (fp32, reads st layer2 h) ----------------
__global__ __launch_bounds__(128) void outproj(const float* __restrict__ st,
                                               const float* __restrict__ w_out,
                                               const float* __restrict__ b_out,
                                               float* __restrict__ out, int tstep)
{
    __shared__ float lh[U_];
    const int b = blockIdx.x, t = threadIdx.x;
    const float* h2 = st + (size_t)b * STLD + 2 * (2 * U_);
    for (int x = t; x < U_; x += 128) lh[x] = h2[x];
    __syncthreads();
    if (t < DIN_) {
        float a0 = 0.f, a1 = 0.f, a2 = 0.f, a3 = 0.f;
        for (int k = 0; k < U_; k += 4) {
            a0 += lh[k + 0] * w_out[(size_t)(k + 0) * DIN_ + t];
            a1 += lh[k + 1] * w_out[(size_t)(k + 1) * DIN_ + t];
            a2 += lh[k + 2] * w_out[(size_t)(k + 2) * DIN_ + t];
            a3 += lh[k + 3] * w_out[(size_t)(k + 3) * DIN_ + t];
        }
        out[(size_t)b * T_ * DIN_ + tstep * DIN_ + t] = a0 + a1 + a2 + a3 + b_out[t];
    }
}

extern "C" void kernel_launch(void* const* d_in, const int* in_sizes, int n_in,
                              void* d_out, int out_size, void* d_ws, size_t ws_size,
                              hipStream_t stream)
{
    const float* z      = (const float*)d_in[0];
    const float* w_init = (const float*)d_in[1];
    const float* b_init = (const float*)d_in[2];
    const float* k0     = (const float*)d_in[3];
    const float* rk0    = (const float*)d_in[4];
    const float* b0     = (const float*)d_in[5];
    const float* k1     = (const float*)d_in[6];
    const float* rk1    = (const float*)d_in[7];
    const float* b1     = (const float*)d_in[8];
    const float* k2     = (const float*)d_in[9];
    const float* rk2    = (const float*)d_in[10];
    const float* b2     = (const float*)d_in[11];
    const float* w_out  = (const float*)d_in[12];
    const float* b_out  = (const float*)d_in[13];
    float* out = (float*)d_out;
    (void)in_sizes; (void)n_in; (void)out_size; (void)ws_size;

    // workspace carve-up (256B aligned), total ~200 MB
    size_t off = 0;
    char* base = (char*)d_ws;
    auto alloc = [&](size_t bytes) { void* p = base + off; off += (bytes + 255) & ~(size_t)255; return p; };
    unsigned short* rk0T = (unsigned short*)alloc((size_t)U_ * G4_ * 2);
    unsigned short* rk1T = (unsigned short*)alloc((size_t)U_ * G4_ * 2);
    unsigned short* rk2T = (unsigned short*)alloc((size_t)U_ * G4_ * 2);
    unsigned short* k1T  = (unsigned short*)alloc((size_t)U_ * G4_ * 2);
    unsigned short* k2T  = (unsigned short*)alloc((size_t)U_ * G4_ * 2);
    unsigned short* wiT  = (unsigned short*)alloc((size_t)STLD * Z_ * 2);
    unsigned short* k0T  = (unsigned short*)alloc((size_t)G4_ * Z_ * 2);
    unsigned short* zb   = (unsigned short*)alloc((size_t)B_ * Z_ * 2);
    unsigned short* hb[3][2];
    for (int l2 = 0; l2 < 3; ++l2)
        for (int p = 0; p < 2; ++p)
            hb[l2][p] = (unsigned short*)alloc((size_t)B_ * U_ * 2);
    float* st  = (float*)alloc((size_t)B_ * STLD * 4);
    float* xk0 = (float*)alloc((size_t)B_ * G4_ * 4);
    float* zg1 = (float*)alloc((size_t)B_ * G4_ * 4);
    float* zg2 = (float*)alloc((size_t)B_ * G4_ * 4);

    // --- one-time conversions ---
    transpose_cvt<<<dim3(STLD / 32, Z_ / 32), 256, 0, stream>>>(w_init, wiT, Z_, STLD, 0);
    transpose_cvt<<<dim3(G4_ / 32, Z_ / 32), 256, 0, stream>>>(k0, k0T, Z_, G4_, DIN_);
    transpose_cvt<<<dim3(G4_ / 32, U_ / 32), 256, 0, stream>>>(rk0, rk0T, U_, G4_, 0);
    transpose_cvt<<<dim3(G4_ / 32, U_ / 32), 256, 0, stream>>>(rk1, rk1T, U_, G4_, 0);
    transpose_cvt<<<dim3(G4_ / 32, U_ / 32), 256, 0, stream>>>(rk2, rk2T, U_, G4_, 0);
    transpose_cvt<<<dim3(G4_ / 32, U_ / 32), 256, 0, stream>>>(k1, k1T, U_, G4_, 0);
    transpose_cvt<<<dim3(G4_ / 32, U_ / 32), 256, 0, stream>>>(k2, k2T, U_, G4_, 0);
    cvt_z<<<dim3(B_ * Z_ / 256), 256, 0, stream>>>(z, zb);

    // --- setup: st = zb @ wiT^T + b_init ; xk0 = zb @ k0T^T + b0 ---
    gemm_plain<<<dim3(STLD / 64), 256, 0, stream>>>(zb, Z_, wiT, b_init, st, STLD);
    gemm_plain<<<dim3(G4_ / 64), 256, 0, stream>>>(zb, Z_, k0T, b0, xk0, G4_);
    hinit<<<dim3(3 * B_ * U_ / 256), 256, 0, stream>>>(st, hb[0][0], hb[1][0], hb[2][0]);

    // --- time loop: 4 launches/step ---
    for (int tstep = 0; tstep < T_; ++tstep) {
        const int p = tstep & 1;
        recA<<<dim3(U_ / 16, 3), 512, 0, stream>>>(hb[0][p], hb[1][p], hb[2][p],
                                                   rk0T, rk1T, rk2T,
                                                   xk0, b1, b2, zg1, zg2,
                                                   st, hb[0][p ^ 1]);
        kgate<<<dim3(U_ / 16), 512, 0, stream>>>(hb[0][p ^ 1], k1T, zg1, st, hb[1][p ^ 1], 1);
        kgate<<<dim3(U_ / 16), 512, 0, stream>>>(hb[1][p ^ 1], k2T, zg2, st, hb[2][p ^ 1], 2);
        outproj<<<dim3(B_), 128, 0, stream>>>(st, w_out, b_out, out, tstep);
    }
}

// Round 5
// 4765.363 us; speedup vs baseline: 4.3634x; 1.5247x over previous
//
#include <hip/hip_runtime.h>
#include <cstdint>

// Problem constants
#define B_   64
#define Z_   512
#define U_   2048
#define T_   32
#define DIN_ 90
#define G4_  8192      // 4*U
#define STLD 12288     // st row stride (fp32 h/c state): h_l = +l*4096, c_l = +l*4096+2048

using bf16x8 = __attribute__((ext_vector_type(8))) short;   // 8 bf16 = 4 VGPRs
using f32x4  = __attribute__((ext_vector_type(4))) float;

#define MFMA(a, b, c) __builtin_amdgcn_mfma_f32_16x16x32_bf16((a), (b), (c), 0, 0, 0)

__device__ __forceinline__ unsigned short f2bf(float f) {
    unsigned int u = __float_as_uint(f);
    unsigned int r = (u + 0x7FFFu + ((u >> 16) & 1u)) >> 16;   // RNE
    return (unsigned short)r;
}
__device__ __forceinline__ float sigf(float x) { return 1.f / (1.f + expf(-x)); }

// ---------------- one-time weight prep ----------------

// Wt[n*K + k] = bf16(W[(row_off+k)*N + n])  -- transpose + convert
__global__ __launch_bounds__(256) void transpose_cvt(const float* __restrict__ W,
                                                     unsigned short* __restrict__ Wt,
                                                     int K, int N, int row_off)
{
    __shared__ float tile[32][33];
    const int nb = blockIdx.x * 32, kb = blockIdx.y * 32;
    const int tx = threadIdx.x & 31, ty = threadIdx.x >> 5;   // 32 x 8
    #pragma unroll
    for (int i = 0; i < 4; ++i)
        tile[ty + i * 8][tx] = W[(size_t)(row_off + kb + ty + i * 8) * N + nb + tx];
    __syncthreads();
    #pragma unroll
    for (int i = 0; i < 4; ++i)
        Wt[(size_t)(nb + ty + i * 8) * K + kb + tx] = f2bf(tile[tx][ty + i * 8]);
}

__global__ __launch_bounds__(256) void cvt_z(const float* __restrict__ z,
                                             unsigned short* __restrict__ zb)
{
    int i = blockIdx.x * 256 + threadIdx.x;        // 64*512
    zb[i] = f2bf(z[i]);
}

// initial h (from st fp32) -> bf16 ping buffers
__global__ __launch_bounds__(256) void hinit(const float* __restrict__ st,
                                             unsigned short* __restrict__ h0,
                                             unsigned short* __restrict__ h1,
                                             unsigned short* __restrict__ h2)
{
    int idx = blockIdx.x * 256 + threadIdx.x;      // 3*64*2048
    int u = idx & 2047, b = (idx >> 11) & 63, ly = idx >> 17;
    float v = st[(size_t)b * STLD + ly * 4096 + u];
    unsigned short* h = (ly == 0) ? h0 : (ly == 1) ? h1 : h2;
    h[(size_t)b * 2048 + u] = f2bf(v);
}

// ---------------- setup GEMMs (K=512): out[64 x N] = A @ Wt^T + bias ----------------
__global__ __launch_bounds__(256) void gemm_plain(const unsigned short* __restrict__ A, int K,
                                                  const unsigned short* __restrict__ Wt,
                                                  const float* __restrict__ bias,
                                                  float* __restrict__ out, int ldo)
{
    const int t = threadIdx.x, wv = t >> 6, l = t & 63;
    const int wm = (wv >> 1) * 32, n0 = blockIdx.x * 64 + (wv & 1) * 32;
    const int lr = l & 15, lk = (l >> 4) * 8;
    f32x4 acc[2][2] = {};
    for (int kt = 0; kt < K; kt += 32) {
        bf16x8 a0 = *(const bf16x8*)(A + (size_t)(wm + lr) * K + kt + lk);
        bf16x8 a1 = *(const bf16x8*)(A + (size_t)(wm + 16 + lr) * K + kt + lk);
        bf16x8 w0 = *(const bf16x8*)(Wt + (size_t)(n0 + lr) * K + kt + lk);
        bf16x8 w1 = *(const bf16x8*)(Wt + (size_t)(n0 + 16 + lr) * K + kt + lk);
        acc[0][0] = MFMA(a0, w0, acc[0][0]);
        acc[0][1] = MFMA(a0, w1, acc[0][1]);
        acc[1][0] = MFMA(a1, w0, acc[1][0]);
        acc[1][1] = MFMA(a1, w1, acc[1][1]);
    }
    #pragma unroll
    for (int mi = 0; mi < 2; ++mi)
        #pragma unroll
        for (int ni = 0; ni < 2; ++ni)
            #pragma unroll
            for (int r = 0; r < 4; ++r) {
                int row = wm + mi * 16 + (l >> 4) * 4 + r;
                int col = n0 + ni * 16 + lr;
                out[(size_t)row * ldo + col] = acc[mi][ni][r] + bias[col];
            }
}

// ---------------- K-split partial GEMM tile (A,Wt stride U_=2048) ----------------
// block 256 = 4 waves (2x2), block tile 64 rows x 64 cols, wave tile 32x32
template<int CHUNK>
__device__ __forceinline__ void gemm_tile(const unsigned short* __restrict__ A,
                                          const unsigned short* __restrict__ Wt,
                                          int k0, int n0base, int t,
                                          float* __restrict__ Pc)
{
    const int wv = t >> 6, l = t & 63;
    const int wm = (wv >> 1) * 32;
    const int n0 = n0base + (wv & 1) * 32;
    const int lr = l & 15, lk = (l >> 4) * 8;
    const unsigned short* ap = A + (size_t)(wm + lr) * U_ + k0 + lk;
    const unsigned short* wp = Wt + (size_t)(n0 + lr) * U_ + k0 + lk;
    f32x4 acc[2][2] = {};
    #pragma unroll 4
    for (int kt = 0; kt < CHUNK; kt += 32) {
        bf16x8 a0 = *(const bf16x8*)(ap + kt);
        bf16x8 a1 = *(const bf16x8*)(ap + (size_t)16 * U_ + kt);
        bf16x8 w0 = *(const bf16x8*)(wp + kt);
        bf16x8 w1 = *(const bf16x8*)(wp + (size_t)16 * U_ + kt);
        acc[0][0] = MFMA(a0, w0, acc[0][0]);
        acc[0][1] = MFMA(a0, w1, acc[0][1]);
        acc[1][0] = MFMA(a1, w0, acc[1][0]);
        acc[1][1] = MFMA(a1, w1, acc[1][1]);
    }
    const int l4 = (l >> 4) * 4;
    #pragma unroll
    for (int mi = 0; mi < 2; ++mi)
        #pragma unroll
        for (int ni = 0; ni < 2; ++ni)
            #pragma unroll
            for (int r = 0; r < 4; ++r) {
                int row = wm + mi * 16 + l4 + r;
                int col = n0 + ni * 16 + lr;
                Pc[(size_t)row * G4_ + col] = acc[mi][ni][r];
            }
}

// rec GEMMs: grid (128 coltiles, 4 chunks, 3 layers); chunk = 512
__global__ __launch_bounds__(256) void rec_split(
    const unsigned short* __restrict__ hb0, const unsigned short* __restrict__ hb1,
    const unsigned short* __restrict__ hb2,
    const unsigned short* __restrict__ rk0T, const unsigned short* __restrict__ rk1T,
    const unsigned short* __restrict__ rk2T,
    float* __restrict__ zgp)
{
    const int ly = blockIdx.z, ck = blockIdx.y;
    const unsigned short* A  = (ly == 0) ? hb0 : (ly == 1) ? hb1 : hb2;
    const unsigned short* Wt = (ly == 0) ? rk0T : (ly == 1) ? rk1T : rk2T;
    float* Pc = zgp + (size_t)(ly * 4 + ck) * B_ * G4_;
    gemm_tile<512>(A, Wt, ck * 512, blockIdx.x * 64, threadIdx.x, Pc);
}

// k-input GEMM: grid (128 coltiles, 8 chunks); chunk = 256
__global__ __launch_bounds__(256) void k_split(const unsigned short* __restrict__ A,
                                               const unsigned short* __restrict__ kT,
                                               float* __restrict__ kp)
{
    const int ck = blockIdx.y;
    gemm_tile<256>(A, kT, ck * 256, blockIdx.x * 64, threadIdx.x,
                   kp + (size_t)ck * B_ * G4_);
}

// ---------------- gate: reduce partials + base -> LSTM cell ----------------
// N1 partials in P1, N2 partials in P2; base = xbase buffer (XB) or bias vector
template<int N1, int N2, bool XB>
__global__ __launch_bounds__(256) void gate_fused(
    const float* __restrict__ P1, const float* __restrict__ P2,
    const float* __restrict__ xbase, const float* __restrict__ bias,
    float* __restrict__ st, unsigned short* __restrict__ hbnew, int ly)
{
    const int idx = blockIdx.x * 256 + threadIdx.x;   // 64*2048
    const int b = idx >> 11, u = idx & 2047;
    float g[4];
    #pragma unroll
    for (int gi = 0; gi < 4; ++gi) {
        const int col = gi * 2048 + u;
        const size_t o = (size_t)b * G4_ + col;
        float s = XB ? xbase[o] : bias[col];
        #pragma unroll
        for (int c = 0; c < N1; ++c) s += P1[(size_t)c * B_ * G4_ + o];
        #pragma unroll
        for (int c = 0; c < N2; ++c) s += P2[(size_t)c * B_ * G4_ + o];
        g[gi] = s;
    }
    float* cp = st + (size_t)b * STLD + ly * 4096 + 2048 + u;
    const float c  = *cp;
    const float cn = sigf(g[1]) * c + sigf(g[0]) * tanhf(g[2]);
    const float hn = sigf(g[3]) * tanhf(cn);
    *cp = cn;
    st[(size_t)b * STLD + ly * 4096 + u] = hn;
    hbnew[(size_t)b * 2048 + u] = f2bf(hn);
}

// ---------------- output projection (fp32, reads st layer2 h) ----------------
__global__ __launch_bounds__(128) void outproj(const float* __restrict__ st,
                                               const float* __restrict__ w_out,
                                               const float* __restrict__ b_out,
                                               float* __restrict__ out, int tstep)
{
    __shared__ float lh[U_];
    const int b = blockIdx.x, t = threadIdx.x;
    const float* h2 = st + (size_t)b * STLD + 2 * (2 * U_);
    for (int x = t; x < U_; x += 128) lh[x] = h2[x];
    __syncthreads();
    if (t < DIN_) {
        float a0 = 0.f, a1 = 0.f, a2 = 0.f, a3 = 0.f;
        for (int k = 0; k < U_; k += 4) {
            a0 += lh[k + 0] * w_out[(size_t)(k + 0) * DIN_ + t];
            a1 += lh[k + 1] * w_out[(size_t)(k + 1) * DIN_ + t];
            a2 += lh[k + 2] * w_out[(size_t)(k + 2) * DIN_ + t];
            a3 += lh[k + 3] * w_out[(size_t)(k + 3) * DIN_ + t];
        }
        out[(size_t)b * T_ * DIN_ + tstep * DIN_ + t] = a0 + a1 + a2 + a3 + b_out[t];
    }
}

extern "C" void kernel_launch(void* const* d_in, const int* in_sizes, int n_in,
                              void* d_out, int out_size, void* d_ws, size_t ws_size,
                              hipStream_t stream)
{
    const float* z      = (const float*)d_in[0];
    const float* w_init = (const float*)d_in[1];
    const float* b_init = (const float*)d_in[2];
    const float* k0     = (const float*)d_in[3];
    const float* rk0    = (const float*)d_in[4];
    const float* b0     = (const float*)d_in[5];
    const float* k1     = (const float*)d_in[6];
    const float* rk1    = (const float*)d_in[7];
    const float* b1     = (const float*)d_in[8];
    const float* k2     = (const float*)d_in[9];
    const float* rk2    = (const float*)d_in[10];
    const float* b2     = (const float*)d_in[11];
    const float* w_out  = (const float*)d_in[12];
    const float* b_out  = (const float*)d_in[13];
    float* out = (float*)d_out;
    (void)in_sizes; (void)n_in; (void)out_size; (void)ws_size;

    // workspace carve-up (256B aligned), total ~215 MB
    size_t off = 0;
    char* base = (char*)d_ws;
    auto alloc = [&](size_t bytes) { void* p = base + off; off += (bytes + 255) & ~(size_t)255; return p; };
    unsigned short* rk0T = (unsigned short*)alloc((size_t)U_ * G4_ * 2);
    unsigned short* rk1T = (unsigned short*)alloc((size_t)U_ * G4_ * 2);
    unsigned short* rk2T = (unsigned short*)alloc((size_t)U_ * G4_ * 2);
    unsigned short* k1T  = (unsigned short*)alloc((size_t)U_ * G4_ * 2);
    unsigned short* k2T  = (unsigned short*)alloc((size_t)U_ * G4_ * 2);
    unsigned short* wiT  = (unsigned short*)alloc((size_t)STLD * Z_ * 2);
    unsigned short* k0T  = (unsigned short*)alloc((size_t)G4_ * Z_ * 2);
    unsigned short* zb   = (unsigned short*)alloc((size_t)B_ * Z_ * 2);
    unsigned short* hb[3][2];
    for (int l2 = 0; l2 < 3; ++l2)
        for (int p = 0; p < 2; ++p)
            hb[l2][p] = (unsigned short*)alloc((size_t)B_ * U_ * 2);
    float* st  = (float*)alloc((size_t)B_ * STLD * 4);
    float* xk0 = (float*)alloc((size_t)B_ * G4_ * 4);
    float* zgp = (float*)alloc((size_t)12 * B_ * G4_ * 4);   // rec partials: [layer*4+chunk]
    float* kp  = (float*)alloc((size_t)8 * B_ * G4_ * 4);    // k-GEMM partials

    // --- one-time conversions ---
    transpose_cvt<<<dim3(STLD / 32, Z_ / 32), 256, 0, stream>>>(w_init, wiT, Z_, STLD, 0);
    transpose_cvt<<<dim3(G4_ / 32, Z_ / 32), 256, 0, stream>>>(k0, k0T, Z_, G4_, DIN_);
    transpose_cvt<<<dim3(G4_ / 32, U_ / 32), 256, 0, stream>>>(rk0, rk0T, U_, G4_, 0);
    transpose_cvt<<<dim3(G4_ / 32, U_ / 32), 256, 0, stream>>>(rk1, rk1T, U_, G4_, 0);
    transpose_cvt<<<dim3(G4_ / 32, U_ / 32), 256, 0, stream>>>(rk2, rk2T, U_, G4_, 0);
    transpose_cvt<<<dim3(G4_ / 32, U_ / 32), 256, 0, stream>>>(k1, k1T, U_, G4_, 0);
    transpose_cvt<<<dim3(G4_ / 32, U_ / 32), 256, 0, stream>>>(k2, k2T, U_, G4_, 0);
    cvt_z<<<dim3(B_ * Z_ / 256), 256, 0, stream>>>(z, zb);

    // --- setup: st = zb @ wiT^T + b_init ; xk0 = zb @ k0T^T + b0 ---
    gemm_plain<<<dim3(STLD / 64), 256, 0, stream>>>(zb, Z_, wiT, b_init, st, STLD);
    gemm_plain<<<dim3(G4_ / 64), 256, 0, stream>>>(zb, Z_, k0T, b0, xk0, G4_);
    hinit<<<dim3(3 * B_ * U_ / 256), 256, 0, stream>>>(st, hb[0][0], hb[1][0], hb[2][0]);

    // --- time loop: 7 launches/step ---
    const int GB = B_ * U_ / 256;   // 512 blocks for gate kernels
    for (int tstep = 0; tstep < T_; ++tstep) {
        const int p = tstep & 1;
        rec_split<<<dim3(G4_ / 64, 4, 3), 256, 0, stream>>>(hb[0][p], hb[1][p], hb[2][p],
                                                            rk0T, rk1T, rk2T, zgp);
        gate_fused<4, 0, true><<<dim3(GB), 256, 0, stream>>>(zgp, nullptr, xk0, nullptr,
                                                             st, hb[0][p ^ 1], 0);
        k_split<<<dim3(G4_ / 64, 8), 256, 0, stream>>>(hb[0][p ^ 1], k1T, kp);
        gate_fused<4, 8, false><<<dim3(GB), 256, 0, stream>>>(zgp + (size_t)4 * B_ * G4_, kp,
                                                              nullptr, b1, st, hb[1][p ^ 1], 1);
        k_split<<<dim3(G4_ / 64, 8), 256, 0, stream>>>(hb[1][p ^ 1], k2T, kp);
        gate_fused<4, 8, false><<<dim3(GB), 256, 0, stream>>>(zgp + (size_t)8 * B_ * G4_, kp,
                                                              nullptr, b2, st, hb[2][p ^ 1], 2);
        outproj<<<dim3(B_), 128, 0, stream>>>(st, w_out, b_out, out, tstep);
    }
}

// Round 6
// 3391.384 us; speedup vs baseline: 6.1312x; 1.4051x over previous
//
#include <hip/hip_runtime.h>
#include <cstdint>

// Problem constants
#define B_   64
#define Z_   512
#define U_   2048
#define T_   32
#define DIN_ 90
#define G4_  8192      // 4*U
#define STLD 12288     // st row stride (fp32 c state lives at +l*4096+2048)

using bf16x8 = __attribute__((ext_vector_type(8))) short;   // 8 bf16 = 4 VGPRs
using f32x4  = __attribute__((ext_vector_type(4))) float;

#define MFMA(a, b, c) __builtin_amdgcn_mfma_f32_16x16x32_bf16((a), (b), (c), 0, 0, 0)

__device__ __forceinline__ unsigned short f2bf(float f) {
    unsigned int u = __float_as_uint(f);
    unsigned int r = (u + 0x7FFFu + ((u >> 16) & 1u)) >> 16;   // RNE
    return (unsigned short)r;
}
__device__ __forceinline__ float sigf(float x) { return 1.f / (1.f + expf(-x)); }

// ---------------- one-time weight prep ----------------

// Wt[n*K + k] = bf16(W[(row_off+k)*N + n])  -- transpose + convert
__global__ __launch_bounds__(256) void transpose_cvt(const float* __restrict__ W,
                                                     unsigned short* __restrict__ Wt,
                                                     int K, int N, int row_off)
{
    __shared__ float tile[32][33];
    const int nb = blockIdx.x * 32, kb = blockIdx.y * 32;
    const int tx = threadIdx.x & 31, ty = threadIdx.x >> 5;   // 32 x 8
    #pragma unroll
    for (int i = 0; i < 4; ++i)
        tile[ty + i * 8][tx] = W[(size_t)(row_off + kb + ty + i * 8) * N + nb + tx];
    __syncthreads();
    #pragma unroll
    for (int i = 0; i < 4; ++i)
        Wt[(size_t)(nb + ty + i * 8) * K + kb + tx] = f2bf(tile[tx][ty + i * 8]);
}

// w_outT[d][k] = bf16(w_out[k*90+d]) for d<90, else 0   (96 x 2048)
__global__ __launch_bounds__(256) void wout_cvt(const float* __restrict__ w_out,
                                                unsigned short* __restrict__ w_outT)
{
    int i = blockIdx.x * 256 + threadIdx.x;        // 96*2048
    int d = i >> 11, k = i & 2047;
    w_outT[i] = (d < DIN_) ? f2bf(w_out[(size_t)k * DIN_ + d]) : (unsigned short)0;
}

__global__ __launch_bounds__(256) void cvt_z(const float* __restrict__ z,
                                             unsigned short* __restrict__ zb)
{
    int i = blockIdx.x * 256 + threadIdx.x;        // 64*512
    zb[i] = f2bf(z[i]);
}

// initial h (from st fp32 setup GEMM) -> bf16 buffers (h0/h1 ping slot0, h2 -> hist slot0)
__global__ __launch_bounds__(256) void hinit(const float* __restrict__ st,
                                             unsigned short* __restrict__ h0,
                                             unsigned short* __restrict__ h1,
                                             unsigned short* __restrict__ h2s0)
{
    int idx = blockIdx.x * 256 + threadIdx.x;      // 3*64*2048
    int u = idx & 2047, b = (idx >> 11) & 63, ly = idx >> 17;
    float v = st[(size_t)b * STLD + ly * 4096 + u];
    unsigned short* h = (ly == 0) ? h0 : (ly == 1) ? h1 : h2s0;
    h[(size_t)b * 2048 + u] = f2bf(v);
}

// ---------------- setup GEMMs (K=512): out[64 x N] = A @ Wt^T + bias ----------------
__global__ __launch_bounds__(256) void gemm_plain(const unsigned short* __restrict__ A, int K,
                                                  const unsigned short* __restrict__ Wt,
                                                  const float* __restrict__ bias,
                                                  float* __restrict__ out, int ldo)
{
    const int t = threadIdx.x, wv = t >> 6, l = t & 63;
    const int wm = (wv >> 1) * 32, n0 = blockIdx.x * 64 + (wv & 1) * 32;
    const int lr = l & 15, lk = (l >> 4) * 8;
    f32x4 acc[2][2] = {};
    for (int kt = 0; kt < K; kt += 32) {
        bf16x8 a0 = *(const bf16x8*)(A + (size_t)(wm + lr) * K + kt + lk);
        bf16x8 a1 = *(const bf16x8*)(A + (size_t)(wm + 16 + lr) * K + kt + lk);
        bf16x8 w0 = *(const bf16x8*)(Wt + (size_t)(n0 + lr) * K + kt + lk);
        bf16x8 w1 = *(const bf16x8*)(Wt + (size_t)(n0 + 16 + lr) * K + kt + lk);
        acc[0][0] = MFMA(a0, w0, acc[0][0]);
        acc[0][1] = MFMA(a0, w1, acc[0][1]);
        acc[1][0] = MFMA(a1, w0, acc[1][0]);
        acc[1][1] = MFMA(a1, w1, acc[1][1]);
    }
    #pragma unroll
    for (int mi = 0; mi < 2; ++mi)
        #pragma unroll
        for (int ni = 0; ni < 2; ++ni)
            #pragma unroll
            for (int r = 0; r < 4; ++r) {
                int row = wm + mi * 16 + (l >> 4) * 4 + r;
                int col = n0 + ni * 16 + lr;
                out[(size_t)row * ldo + col] = acc[mi][ni][r] + bias[col];
            }
}

// ---------------- K-split partial GEMM tile (A,Wt stride U_=2048) ----------------
// block 256 = 4 waves (2x2), block tile 64 rows x 64 cols, wave tile 32x32
template<int CHUNK>
__device__ __forceinline__ void gemm_tile(const unsigned short* __restrict__ A,
                                          const unsigned short* __restrict__ Wt,
                                          int k0, int n0base, int t,
                                          float* __restrict__ Pc)
{
    const int wv = t >> 6, l = t & 63;
    const int wm = (wv >> 1) * 32;
    const int n0 = n0base + (wv & 1) * 32;
    const int lr = l & 15, lk = (l >> 4) * 8;
    const unsigned short* ap = A + (size_t)(wm + lr) * U_ + k0 + lk;
    const unsigned short* wp = Wt + (size_t)(n0 + lr) * U_ + k0 + lk;
    f32x4 acc[2][2] = {};
    #pragma unroll 4
    for (int kt = 0; kt < CHUNK; kt += 32) {
        bf16x8 a0 = *(const bf16x8*)(ap + kt);
        bf16x8 a1 = *(const bf16x8*)(ap + (size_t)16 * U_ + kt);
        bf16x8 w0 = *(const bf16x8*)(wp + kt);
        bf16x8 w1 = *(const bf16x8*)(wp + (size_t)16 * U_ + kt);
        acc[0][0] = MFMA(a0, w0, acc[0][0]);
        acc[0][1] = MFMA(a0, w1, acc[0][1]);
        acc[1][0] = MFMA(a1, w0, acc[1][0]);
        acc[1][1] = MFMA(a1, w1, acc[1][1]);
    }
    const int l4 = (l >> 4) * 4;
    #pragma unroll
    for (int mi = 0; mi < 2; ++mi)
        #pragma unroll
        for (int ni = 0; ni < 2; ++ni)
            #pragma unroll
            for (int r = 0; r < 4; ++r) {
                int row = wm + mi * 16 + l4 + r;
                int col = n0 + ni * 16 + lr;
                Pc[(size_t)row * G4_ + col] = acc[mi][ni][r];
            }
}

// rec GEMMs: grid (128 coltiles, 4 chunks, 3 layers); chunk = 512
__global__ __launch_bounds__(256) void rec_split(
    const unsigned short* __restrict__ hb0, const unsigned short* __restrict__ hb1,
    const unsigned short* __restrict__ hb2,
    const unsigned short* __restrict__ rk0T, const unsigned short* __restrict__ rk1T,
    const unsigned short* __restrict__ rk2T,
    float* __restrict__ zgp)
{
    const int ly = blockIdx.z, ck = blockIdx.y;
    const unsigned short* A  = (ly == 0) ? hb0 : (ly == 1) ? hb1 : hb2;
    const unsigned short* Wt = (ly == 0) ? rk0T : (ly == 1) ? rk1T : rk2T;
    float* Pc = zgp + (size_t)(ly * 4 + ck) * B_ * G4_;
    gemm_tile<512>(A, Wt, ck * 512, blockIdx.x * 64, threadIdx.x, Pc);
}

// k-input GEMM: grid (128 coltiles, 8 chunks); chunk = 256
__global__ __launch_bounds__(256) void k_split(const unsigned short* __restrict__ A,
                                               const unsigned short* __restrict__ kT,
                                               float* __restrict__ kp)
{
    const int ck = blockIdx.y;
    gemm_tile<256>(A, kT, ck * 256, blockIdx.x * 64, threadIdx.x,
                   kp + (size_t)ck * B_ * G4_);
}

// ---------------- gate: reduce partials + base -> LSTM cell ----------------
// N1 partials in P1, N2 partials in P2; base = xbase buffer (XB) or bias vector
template<int N1, int N2, bool XB>
__global__ __launch_bounds__(256) void gate_fused(
    const float* __restrict__ P1, const float* __restrict__ P2,
    const float* __restrict__ xbase, const float* __restrict__ bias,
    float* __restrict__ st, unsigned short* __restrict__ hbnew, int ly)
{
    const int idx = blockIdx.x * 256 + threadIdx.x;   // 64*2048
    const int b = idx >> 11, u = idx & 2047;
    float g[4];
    #pragma unroll
    for (int gi = 0; gi < 4; ++gi) {
        const int col = gi * 2048 + u;
        const size_t o = (size_t)b * G4_ + col;
        float s = XB ? xbase[o] : bias[col];
        #pragma unroll
        for (int c = 0; c < N1; ++c) s += P1[(size_t)c * B_ * G4_ + o];
        #pragma unroll
        for (int c = 0; c < N2; ++c) s += P2[(size_t)c * B_ * G4_ + o];
        g[gi] = s;
    }
    float* cp = st + (size_t)b * STLD + ly * 4096 + 2048 + u;
    const float c  = *cp;
    const float cn = sigf(g[1]) * c + sigf(g[0]) * tanhf(g[2]);
    const float hn = sigf(g[3]) * tanhf(cn);
    *cp = cn;
    hbnew[(size_t)b * 2048 + u] = f2bf(hn);
}

// ---------------- batched output projection: ONE GEMM after the time loop ----------------
// M = T*B = 2048 rows (r = t*64 + b) from h2hist slots 1..T, N = 96 (cols >= 90 dropped),
// K = 2048. grid 32 blocks x 256 thr (4 waves of 16 rows); B-panel L2-resident.
__global__ __launch_bounds__(256) void outproj_all(const unsigned short* __restrict__ h2h,
                                                   const unsigned short* __restrict__ w_outT,
                                                   const float* __restrict__ b_out,
                                                   float* __restrict__ out)
{
    const int t = threadIdx.x, wv = t >> 6, l = t & 63;
    const int m0 = blockIdx.x * 64 + wv * 16;
    const int lr = l & 15, lk = (l >> 4) * 8;
    const unsigned short* ap = h2h + (size_t)(m0 + lr) * U_ + lk;
    f32x4 acc[6] = {};
    for (int kt = 0; kt < U_; kt += 32) {
        bf16x8 af = *(const bf16x8*)(ap + kt);
        #pragma unroll
        for (int n = 0; n < 6; ++n) {
            bf16x8 wf = *(const bf16x8*)(w_outT + (size_t)(n * 16 + lr) * U_ + kt + lk);
            acc[n] = MFMA(af, wf, acc[n]);
        }
    }
    const int l4 = (l >> 4) * 4;
    #pragma unroll
    for (int n = 0; n < 6; ++n) {
        const int col = n * 16 + lr;
        if (col < DIN_) {
            #pragma unroll
            for (int r = 0; r < 4; ++r) {
                int row = m0 + l4 + r;                  // = tstep*64 + b
                int tt = row >> 6, b = row & 63;
                out[((size_t)b * T_ + tt) * DIN_ + col] = acc[n][r] + b_out[col];
            }
        }
    }
}

extern "C" void kernel_launch(void* const* d_in, const int* in_sizes, int n_in,
                              void* d_out, int out_size, void* d_ws, size_t ws_size,
                              hipStream_t stream)
{
    const float* z      = (const float*)d_in[0];
    const float* w_init = (const float*)d_in[1];
    const float* b_init = (const float*)d_in[2];
    const float* k0     = (const float*)d_in[3];
    const float* rk0    = (const float*)d_in[4];
    const float* b0     = (const float*)d_in[5];
    const float* k1     = (const float*)d_in[6];
    const float* rk1    = (const float*)d_in[7];
    const float* b1     = (const float*)d_in[8];
    const float* k2     = (const float*)d_in[9];
    const float* rk2    = (const float*)d_in[10];
    const float* b2     = (const float*)d_in[11];
    const float* w_out  = (const float*)d_in[12];
    const float* b_out  = (const float*)d_in[13];
    float* out = (float*)d_out;
    (void)in_sizes; (void)n_in; (void)out_size; (void)ws_size;

    // workspace carve-up (256B aligned), total ~225 MB
    size_t off = 0;
    char* base = (char*)d_ws;
    auto alloc = [&](size_t bytes) { void* p = base + off; off += (bytes + 255) & ~(size_t)255; return p; };
    unsigned short* rk0T = (unsigned short*)alloc((size_t)U_ * G4_ * 2);
    unsigned short* rk1T = (unsigned short*)alloc((size_t)U_ * G4_ * 2);
    unsigned short* rk2T = (unsigned short*)alloc((size_t)U_ * G4_ * 2);
    unsigned short* k1T  = (unsigned short*)alloc((size_t)U_ * G4_ * 2);
    unsigned short* k2T  = (unsigned short*)alloc((size_t)U_ * G4_ * 2);
    unsigned short* wiT  = (unsigned short*)alloc((size_t)STLD * Z_ * 2);
    unsigned short* k0T  = (unsigned short*)alloc((size_t)G4_ * Z_ * 2);
    unsigned short* woT  = (unsigned short*)alloc((size_t)96 * U_ * 2);
    unsigned short* zb   = (unsigned short*)alloc((size_t)B_ * Z_ * 2);
    unsigned short* hb[2][2];
    for (int l2 = 0; l2 < 2; ++l2)
        for (int p = 0; p < 2; ++p)
            hb[l2][p] = (unsigned short*)alloc((size_t)B_ * U_ * 2);
    unsigned short* h2hist = (unsigned short*)alloc((size_t)(T_ + 1) * B_ * U_ * 2);
    float* st  = (float*)alloc((size_t)B_ * STLD * 4);
    float* xk0 = (float*)alloc((size_t)B_ * G4_ * 4);
    float* zgp = (float*)alloc((size_t)12 * B_ * G4_ * 4);   // rec partials: [layer*4+chunk]
    float* kp  = (float*)alloc((size_t)8 * B_ * G4_ * 4);    // k-GEMM partials

    // --- one-time conversions ---
    transpose_cvt<<<dim3(STLD / 32, Z_ / 32), 256, 0, stream>>>(w_init, wiT, Z_, STLD, 0);
    transpose_cvt<<<dim3(G4_ / 32, Z_ / 32), 256, 0, stream>>>(k0, k0T, Z_, G4_, DIN_);
    transpose_cvt<<<dim3(G4_ / 32, U_ / 32), 256, 0, stream>>>(rk0, rk0T, U_, G4_, 0);
    transpose_cvt<<<dim3(G4_ / 32, U_ / 32), 256, 0, stream>>>(rk1, rk1T, U_, G4_, 0);
    transpose_cvt<<<dim3(G4_ / 32, U_ / 32), 256, 0, stream>>>(rk2, rk2T, U_, G4_, 0);
    transpose_cvt<<<dim3(G4_ / 32, U_ / 32), 256, 0, stream>>>(k1, k1T, U_, G4_, 0);
    transpose_cvt<<<dim3(G4_ / 32, U_ / 32), 256, 0, stream>>>(k2, k2T, U_, G4_, 0);
    wout_cvt<<<dim3(96 * U_ / 256), 256, 0, stream>>>(w_out, woT);
    cvt_z<<<dim3(B_ * Z_ / 256), 256, 0, stream>>>(z, zb);

    // --- setup: st = zb @ wiT^T + b_init ; xk0 = zb @ k0T^T + b0 ---
    gemm_plain<<<dim3(STLD / 64), 256, 0, stream>>>(zb, Z_, wiT, b_init, st, STLD);
    gemm_plain<<<dim3(G4_ / 64), 256, 0, stream>>>(zb, Z_, k0T, b0, xk0, G4_);
    hinit<<<dim3(3 * B_ * U_ / 256), 256, 0, stream>>>(st, hb[0][0], hb[1][0], h2hist);

    // --- time loop: 6 launches/step ---
    const int GB = B_ * U_ / 256;   // 512 blocks for gate kernels
    for (int tstep = 0; tstep < T_; ++tstep) {
        const int p = tstep & 1;
        rec_split<<<dim3(G4_ / 64, 4, 3), 256, 0, stream>>>(
            hb[0][p], hb[1][p], h2hist + (size_t)tstep * B_ * U_,
            rk0T, rk1T, rk2T, zgp);
        gate_fused<4, 0, true><<<dim3(GB), 256, 0, stream>>>(zgp, nullptr, xk0, nullptr,
                                                             st, hb[0][p ^ 1], 0);
        k_split<<<dim3(G4_ / 64, 8), 256, 0, stream>>>(hb[0][p ^ 1], k1T, kp);
        gate_fused<4, 8, false><<<dim3(GB), 256, 0, stream>>>(zgp + (size_t)4 * B_ * G4_, kp,
                                                              nullptr, b1, st, hb[1][p ^ 1], 1);
        k_split<<<dim3(G4_ / 64, 8), 256, 0, stream>>>(hb[1][p ^ 1], k2T, kp);
        gate_fused<4, 8, false><<<dim3(GB), 256, 0, stream>>>(zgp + (size_t)8 * B_ * G4_, kp,
                                                              nullptr, b2, st,
                                                              h2hist + (size_t)(tstep + 1) * B_ * U_, 2);
    }
    // --- all 32 output projections in one GEMM ---
    outproj_all<<<dim3(T_ * B_ / 64), 256, 0, stream>>>(h2hist + (size_t)B_ * U_, woT, b_out, out);
}

// Round 7
// 2762.962 us; speedup vs baseline: 7.5257x; 1.2274x over previous
//
#include <hip/hip_runtime.h>
#include <cstdint>

// Problem constants
#define B_   64
#define Z_   512
#define U_   2048
#define T_   32
#define DIN_ 90
#define G4_  8192      // 4*U
#define STLD 12288     // st row stride (fp32 c state lives at +l*4096+2048)

using bf16x8 = __attribute__((ext_vector_type(8))) short;   // 8 bf16 = 4 VGPRs
using f32x4  = __attribute__((ext_vector_type(4))) float;

#define MFMA(a, b, c) __builtin_amdgcn_mfma_f32_16x16x32_bf16((a), (b), (c), 0, 0, 0)

__device__ __forceinline__ unsigned short f2bf(float f) {
    unsigned int u = __float_as_uint(f);
    unsigned int r = (u + 0x7FFFu + ((u >> 16) & 1u)) >> 16;   // RNE
    return (unsigned short)r;
}
__device__ __forceinline__ float sigf(float x) { return 1.f / (1.f + expf(-x)); }

// ---------------- one-time weight prep ----------------

// Wt[n*K + k] = bf16(W[(row_off+k)*N + n])  -- transpose + convert
__global__ __launch_bounds__(256) void transpose_cvt(const float* __restrict__ W,
                                                     unsigned short* __restrict__ Wt,
                                                     int K, int N, int row_off)
{
    __shared__ float tile[32][33];
    const int nb = blockIdx.x * 32, kb = blockIdx.y * 32;
    const int tx = threadIdx.x & 31, ty = threadIdx.x >> 5;   // 32 x 8
    #pragma unroll
    for (int i = 0; i < 4; ++i)
        tile[ty + i * 8][tx] = W[(size_t)(row_off + kb + ty + i * 8) * N + nb + tx];
    __syncthreads();
    #pragma unroll
    for (int i = 0; i < 4; ++i)
        Wt[(size_t)(nb + ty + i * 8) * K + kb + tx] = f2bf(tile[tx][ty + i * 8]);
}

// w_outT[d][k] = bf16(w_out[k*90+d]) for d<90, else 0   (96 x 2048)
__global__ __launch_bounds__(256) void wout_cvt(const float* __restrict__ w_out,
                                                unsigned short* __restrict__ w_outT)
{
    int i = blockIdx.x * 256 + threadIdx.x;        // 96*2048
    int d = i >> 11, k = i & 2047;
    w_outT[i] = (d < DIN_) ? f2bf(w_out[(size_t)k * DIN_ + d]) : (unsigned short)0;
}

__global__ __launch_bounds__(256) void cvt_z(const float* __restrict__ z,
                                             unsigned short* __restrict__ zb)
{
    int i = blockIdx.x * 256 + threadIdx.x;        // 64*512
    zb[i] = f2bf(z[i]);
}

// initial h (from st fp32 setup GEMM) -> bf16 buffers (h0/h1 ping slot0, h2 -> hist slot0)
__global__ __launch_bounds__(256) void hinit(const float* __restrict__ st,
                                             unsigned short* __restrict__ h0,
                                             unsigned short* __restrict__ h1,
                                             unsigned short* __restrict__ h2s0)
{
    int idx = blockIdx.x * 256 + threadIdx.x;      // 3*64*2048
    int u = idx & 2047, b = (idx >> 11) & 63, ly = idx >> 17;
    float v = st[(size_t)b * STLD + ly * 4096 + u];
    unsigned short* h = (ly == 0) ? h0 : (ly == 1) ? h1 : h2s0;
    h[(size_t)b * 2048 + u] = f2bf(v);
}

// ---------------- setup GEMMs (K=512): out[64 x N] = A @ Wt^T + bias ----------------
__global__ __launch_bounds__(256) void gemm_plain(const unsigned short* __restrict__ A, int K,
                                                  const unsigned short* __restrict__ Wt,
                                                  const float* __restrict__ bias,
                                                  float* __restrict__ out, int ldo)
{
    const int t = threadIdx.x, wv = t >> 6, l = t & 63;
    const int wm = (wv >> 1) * 32, n0 = blockIdx.x * 64 + (wv & 1) * 32;
    const int lr = l & 15, lk = (l >> 4) * 8;
    f32x4 acc[2][2] = {};
    for (int kt = 0; kt < K; kt += 32) {
        bf16x8 a0 = *(const bf16x8*)(A + (size_t)(wm + lr) * K + kt + lk);
        bf16x8 a1 = *(const bf16x8*)(A + (size_t)(wm + 16 + lr) * K + kt + lk);
        bf16x8 w0 = *(const bf16x8*)(Wt + (size_t)(n0 + lr) * K + kt + lk);
        bf16x8 w1 = *(const bf16x8*)(Wt + (size_t)(n0 + 16 + lr) * K + kt + lk);
        acc[0][0] = MFMA(a0, w0, acc[0][0]);
        acc[0][1] = MFMA(a0, w1, acc[0][1]);
        acc[1][0] = MFMA(a1, w0, acc[1][0]);
        acc[1][1] = MFMA(a1, w1, acc[1][1]);
    }
    #pragma unroll
    for (int mi = 0; mi < 2; ++mi)
        #pragma unroll
        for (int ni = 0; ni < 2; ++ni)
            #pragma unroll
            for (int r = 0; r < 4; ++r) {
                int row = wm + mi * 16 + (l >> 4) * 4 + r;
                int col = n0 + ni * 16 + lr;
                out[(size_t)row * ldo + col] = acc[mi][ni][r] + bias[col];
            }
}

// ---------------- K-split partial GEMM tile, 2-stage register pipeline ----------------
// block 256 = 4 waves (2 row-halves x 2 col-halves), block tile 64 x 128,
// wave tile 32 x 64. 12 loads in flight per wave. Nontemporal partial stores.
// NOTE: prefetch overruns the chunk by <=128 B (reads next row / next ws buffer;
// ws is tail-padded so this never faults and values are never used).
template<int CHUNK>
__device__ __forceinline__ void gemm_tile2(const unsigned short* __restrict__ A,
                                           const unsigned short* __restrict__ Wt,
                                           int k0, int n0base, int t,
                                           float* __restrict__ Pc)
{
    const int wv = t >> 6, l = t & 63;
    const int wm = (wv >> 1) * 32;
    const int n0 = n0base + (wv & 1) * 64;
    const int lr = l & 15, lk = (l >> 4) * 8;
    const unsigned short* ap = A + (size_t)(wm + lr) * U_ + k0 + lk;
    const unsigned short* wp = Wt + (size_t)(n0 + lr) * U_ + k0 + lk;
    const size_t r16 = (size_t)16 * U_;

    f32x4 acc[2][4] = {};
    // stage A (k offset 0)
    bf16x8 a0 = *(const bf16x8*)(ap);
    bf16x8 a1 = *(const bf16x8*)(ap + r16);
    bf16x8 w0 = *(const bf16x8*)(wp);
    bf16x8 w1 = *(const bf16x8*)(wp + r16);
    bf16x8 w2 = *(const bf16x8*)(wp + 2 * r16);
    bf16x8 w3 = *(const bf16x8*)(wp + 3 * r16);

    for (int kt = 0; kt < CHUNK; kt += 64) {
        // stage B loads (kt+32) issue before stage-A MFMAs
        bf16x8 b0 = *(const bf16x8*)(ap + kt + 32);
        bf16x8 b1 = *(const bf16x8*)(ap + r16 + kt + 32);
        bf16x8 x0 = *(const bf16x8*)(wp + kt + 32);
        bf16x8 x1 = *(const bf16x8*)(wp + r16 + kt + 32);
        bf16x8 x2 = *(const bf16x8*)(wp + 2 * r16 + kt + 32);
        bf16x8 x3 = *(const bf16x8*)(wp + 3 * r16 + kt + 32);
        acc[0][0] = MFMA(a0, w0, acc[0][0]);
        acc[0][1] = MFMA(a0, w1, acc[0][1]);
        acc[0][2] = MFMA(a0, w2, acc[0][2]);
        acc[0][3] = MFMA(a0, w3, acc[0][3]);
        acc[1][0] = MFMA(a1, w0, acc[1][0]);
        acc[1][1] = MFMA(a1, w1, acc[1][1]);
        acc[1][2] = MFMA(a1, w2, acc[1][2]);
        acc[1][3] = MFMA(a1, w3, acc[1][3]);
        // stage A loads (kt+64; last iteration prefetches dead data, never used)
        a0 = *(const bf16x8*)(ap + kt + 64);
        a1 = *(const bf16x8*)(ap + r16 + kt + 64);
        w0 = *(const bf16x8*)(wp + kt + 64);
        w1 = *(const bf16x8*)(wp + r16 + kt + 64);
        w2 = *(const bf16x8*)(wp + 2 * r16 + kt + 64);
        w3 = *(const bf16x8*)(wp + 3 * r16 + kt + 64);
        acc[0][0] = MFMA(b0, x0, acc[0][0]);
        acc[0][1] = MFMA(b0, x1, acc[0][1]);
        acc[0][2] = MFMA(b0, x2, acc[0][2]);
        acc[0][3] = MFMA(b0, x3, acc[0][3]);
        acc[1][0] = MFMA(b1, x0, acc[1][0]);
        acc[1][1] = MFMA(b1, x1, acc[1][1]);
        acc[1][2] = MFMA(b1, x2, acc[1][2]);
        acc[1][3] = MFMA(b1, x3, acc[1][3]);
    }
    const int l4 = (l >> 4) * 4;
    #pragma unroll
    for (int mi = 0; mi < 2; ++mi)
        #pragma unroll
        for (int ni = 0; ni < 4; ++ni)
            #pragma unroll
            for (int r = 0; r < 4; ++r) {
                int row = wm + mi * 16 + l4 + r;
                int col = n0 + ni * 16 + lr;
                __builtin_nontemporal_store(acc[mi][ni][r], &Pc[(size_t)row * G4_ + col]);
            }
}

// rec GEMMs: grid (64 coltiles, 4 chunks, 3 layers); chunk = 512
__global__ __launch_bounds__(256, 4) void rec_split(
    const unsigned short* __restrict__ hb0, const unsigned short* __restrict__ hb1,
    const unsigned short* __restrict__ hb2,
    const unsigned short* __restrict__ rk0T, const unsigned short* __restrict__ rk1T,
    const unsigned short* __restrict__ rk2T,
    float* __restrict__ zgp)
{
    const int ly = blockIdx.z, ck = blockIdx.y;
    const unsigned short* A  = (ly == 0) ? hb0 : (ly == 1) ? hb1 : hb2;
    const unsigned short* Wt = (ly == 0) ? rk0T : (ly == 1) ? rk1T : rk2T;
    float* Pc = zgp + (size_t)(ly * 4 + ck) * B_ * G4_;
    gemm_tile2<512>(A, Wt, ck * 512, blockIdx.x * 128, threadIdx.x, Pc);
}

// k-input GEMM: grid (64 coltiles, 8 chunks); chunk = 256
__global__ __launch_bounds__(256, 4) void k_split(const unsigned short* __restrict__ A,
                                                  const unsigned short* __restrict__ kT,
                                                  float* __restrict__ kp)
{
    const int ck = blockIdx.y;
    gemm_tile2<256>(A, kT, ck * 256, blockIdx.x * 128, threadIdx.x,
                    kp + (size_t)ck * B_ * G4_);
}

// ---------------- gate: reduce partials + base -> LSTM cell ----------------
// N1 partials in P1, N2 partials in P2; base = xbase buffer (XB) or bias vector
template<int N1, int N2, bool XB>
__global__ __launch_bounds__(256) void gate_fused(
    const float* __restrict__ P1, const float* __restrict__ P2,
    const float* __restrict__ xbase, const float* __restrict__ bias,
    float* __restrict__ st, unsigned short* __restrict__ hbnew, int ly)
{
    const int idx = blockIdx.x * 256 + threadIdx.x;   // 64*2048
    const int b = idx >> 11, u = idx & 2047;
    float g[4];
    #pragma unroll
    for (int gi = 0; gi < 4; ++gi) {
        const int col = gi * 2048 + u;
        const size_t o = (size_t)b * G4_ + col;
        float s = XB ? xbase[o] : bias[col];
        #pragma unroll
        for (int c = 0; c < N1; ++c) s += __builtin_nontemporal_load(&P1[(size_t)c * B_ * G4_ + o]);
        #pragma unroll
        for (int c = 0; c < N2; ++c) s += __builtin_nontemporal_load(&P2[(size_t)c * B_ * G4_ + o]);
        g[gi] = s;
    }
    float* cp = st + (size_t)b * STLD + ly * 4096 + 2048 + u;
    const float c  = *cp;
    const float cn = sigf(g[1]) * c + sigf(g[0]) * tanhf(g[2]);
    const float hn = sigf(g[3]) * tanhf(cn);
    *cp = cn;
    hbnew[(size_t)b * 2048 + u] = f2bf(hn);
}

// ---------------- batched output projection: ONE GEMM after the time loop ----------------
__global__ __launch_bounds__(256) void outproj_all(const unsigned short* __restrict__ h2h,
                                                   const unsigned short* __restrict__ w_outT,
                                                   const float* __restrict__ b_out,
                                                   float* __restrict__ out)
{
    const int t = threadIdx.x, wv = t >> 6, l = t & 63;
    const int m0 = blockIdx.x * 64 + wv * 16;
    const int lr = l & 15, lk = (l >> 4) * 8;
    const unsigned short* ap = h2h + (size_t)(m0 + lr) * U_ + lk;
    f32x4 acc[6] = {};
    for (int kt = 0; kt < U_; kt += 32) {
        bf16x8 af = *(const bf16x8*)(ap + kt);
        #pragma unroll
        for (int n = 0; n < 6; ++n) {
            bf16x8 wf = *(const bf16x8*)(w_outT + (size_t)(n * 16 + lr) * U_ + kt + lk);
            acc[n] = MFMA(af, wf, acc[n]);
        }
    }
    const int l4 = (l >> 4) * 4;
    #pragma unroll
    for (int n = 0; n < 6; ++n) {
        const int col = n * 16 + lr;
        if (col < DIN_) {
            #pragma unroll
            for (int r = 0; r < 4; ++r) {
                int row = m0 + l4 + r;                  // = tstep*64 + b
                int tt = row >> 6, b = row & 63;
                out[((size_t)b * T_ + tt) * DIN_ + col] = acc[n][r] + b_out[col];
            }
        }
    }
}

extern "C" void kernel_launch(void* const* d_in, const int* in_sizes, int n_in,
                              void* d_out, int out_size, void* d_ws, size_t ws_size,
                              hipStream_t stream)
{
    const float* z      = (const float*)d_in[0];
    const float* w_init = (const float*)d_in[1];
    const float* b_init = (const float*)d_in[2];
    const float* k0     = (const float*)d_in[3];
    const float* rk0    = (const float*)d_in[4];
    const float* b0     = (const float*)d_in[5];
    const float* k1     = (const float*)d_in[6];
    const float* rk1    = (const float*)d_in[7];
    const float* b1     = (const float*)d_in[8];
    const float* k2     = (const float*)d_in[9];
    const float* rk2    = (const float*)d_in[10];
    const float* b2     = (const float*)d_in[11];
    const float* w_out  = (const float*)d_in[12];
    const float* b_out  = (const float*)d_in[13];
    float* out = (float*)d_out;
    (void)in_sizes; (void)n_in; (void)out_size; (void)ws_size;

    // workspace carve-up (256B aligned), total ~225 MB (+tail pad for prefetch overrun)
    size_t off = 0;
    char* base = (char*)d_ws;
    auto alloc = [&](size_t bytes) { void* p = base + off; off += (bytes + 255) & ~(size_t)255; return p; };
    unsigned short* rk0T = (unsigned short*)alloc((size_t)U_ * G4_ * 2);
    unsigned short* rk1T = (unsigned short*)alloc((size_t)U_ * G4_ * 2);
    unsigned short* rk2T = (unsigned short*)alloc((size_t)U_ * G4_ * 2);
    unsigned short* k1T  = (unsigned short*)alloc((size_t)U_ * G4_ * 2);
    unsigned short* k2T  = (unsigned short*)alloc((size_t)U_ * G4_ * 2);
    unsigned short* wiT  = (unsigned short*)alloc((size_t)STLD * Z_ * 2);
    unsigned short* k0T  = (unsigned short*)alloc((size_t)G4_ * Z_ * 2);
    unsigned short* woT  = (unsigned short*)alloc((size_t)96 * U_ * 2);
    unsigned short* zb   = (unsigned short*)alloc((size_t)B_ * Z_ * 2);
    unsigned short* hb[2][2];
    for (int l2 = 0; l2 < 2; ++l2)
        for (int p = 0; p < 2; ++p)
            hb[l2][p] = (unsigned short*)alloc((size_t)B_ * U_ * 2);
    unsigned short* h2hist = (unsigned short*)alloc((size_t)(T_ + 1) * B_ * U_ * 2);
    float* st  = (float*)alloc((size_t)B_ * STLD * 4);
    float* xk0 = (float*)alloc((size_t)B_ * G4_ * 4);
    float* zgp = (float*)alloc((size_t)12 * B_ * G4_ * 4);   // rec partials: [layer*4+chunk]
    float* kp  = (float*)alloc((size_t)8 * B_ * G4_ * 4);    // k-GEMM partials
    (void)alloc(4096);                                       // tail pad (prefetch overrun)

    // --- one-time conversions ---
    transpose_cvt<<<dim3(STLD / 32, Z_ / 32), 256, 0, stream>>>(w_init, wiT, Z_, STLD, 0);
    transpose_cvt<<<dim3(G4_ / 32, Z_ / 32), 256, 0, stream>>>(k0, k0T, Z_, G4_, DIN_);
    transpose_cvt<<<dim3(G4_ / 32, U_ / 32), 256, 0, stream>>>(rk0, rk0T, U_, G4_, 0);
    transpose_cvt<<<dim3(G4_ / 32, U_ / 32), 256, 0, stream>>>(rk1, rk1T, U_, G4_, 0);
    transpose_cvt<<<dim3(G4_ / 32, U_ / 32), 256, 0, stream>>>(rk2, rk2T, U_, G4_, 0);
    transpose_cvt<<<dim3(G4_ / 32, U_ / 32), 256, 0, stream>>>(k1, k1T, U_, G4_, 0);
    transpose_cvt<<<dim3(G4_ / 32, U_ / 32), 256, 0, stream>>>(k2, k2T, U_, G4_, 0);
    wout_cvt<<<dim3(96 * U_ / 256), 256, 0, stream>>>(w_out, woT);
    cvt_z<<<dim3(B_ * Z_ / 256), 256, 0, stream>>>(z, zb);

    // --- setup: st = zb @ wiT^T + b_init ; xk0 = zb @ k0T^T + b0 ---
    gemm_plain<<<dim3(STLD / 64), 256, 0, stream>>>(zb, Z_, wiT, b_init, st, STLD);
    gemm_plain<<<dim3(G4_ / 64), 256, 0, stream>>>(zb, Z_, k0T, b0, xk0, G4_);
    hinit<<<dim3(3 * B_ * U_ / 256), 256, 0, stream>>>(st, hb[0][0], hb[1][0], h2hist);

    // --- time loop: 6 launches/step ---
    const int GB = B_ * U_ / 256;   // 512 blocks for gate kernels
    for (int tstep = 0; tstep < T_; ++tstep) {
        const int p = tstep & 1;
        rec_split<<<dim3(G4_ / 128, 4, 3), 256, 0, stream>>>(
            hb[0][p], hb[1][p], h2hist + (size_t)tstep * B_ * U_,
            rk0T, rk1T, rk2T, zgp);
        gate_fused<4, 0, true><<<dim3(GB), 256, 0, stream>>>(zgp, nullptr, xk0, nullptr,
                                                             st, hb[0][p ^ 1], 0);
        k_split<<<dim3(G4_ / 128, 8), 256, 0, stream>>>(hb[0][p ^ 1], k1T, kp);
        gate_fused<4, 8, false><<<dim3(GB), 256, 0, stream>>>(zgp + (size_t)4 * B_ * G4_, kp,
                                                              nullptr, b1, st, hb[1][p ^ 1], 1);
        k_split<<<dim3(G4_ / 128, 8), 256, 0, stream>>>(hb[1][p ^ 1], k2T, kp);
        gate_fused<4, 8, false><<<dim3(GB), 256, 0, stream>>>(zgp + (size_t)8 * B_ * G4_, kp,
                                                              nullptr, b2, st,
                                                              h2hist + (size_t)(tstep + 1) * B_ * U_, 2);
    }
    // --- all 32 output projections in one GEMM ---
    outproj_all<<<dim3(T_ * B_ / 64), 256, 0, stream>>>(h2hist + (size_t)B_ * U_, woT, b_out, out);
}